// Round 7
// baseline (260.513 us; speedup 1.0000x reference)
//
#include <hip/hip_runtime.h>
#include <hip/hip_bf16.h>
#include <hip/hip_fp8.h>
#include <cstdint>
#include <cstddef>

// Problem constants (x = (8192, 768) fp32)
#define GN 8192
#define GD 768           // elements per row; fp8 => 768 bytes per row
#define NB 64            // 128-row blocks
#define NTILE 2080       // NB*(NB+1)/2 triangular tiles
#define KI 6             // 768 / 128 K-iterations

typedef __attribute__((ext_vector_type(4))) int i32x4;
typedef __attribute__((ext_vector_type(8))) int i32x8;
typedef __attribute__((ext_vector_type(4))) float f32x4;

// load a 32-byte MFMA fragment straight from global (16B-aligned)
__device__ __forceinline__ i32x8 ldg32(const unsigned char* p) {
    i32x4 lo = *(const i32x4*)p;
    i32x4 hi = *(const i32x4*)(p + 16);
    return __builtin_shufflevector(lo, hi, 0, 1, 2, 3, 4, 5, 6, 7);
}

// ---------------- Kernel 1: fp8 e4m3 quantize + row sum-of-squares of the
// DEQUANTIZED values (makes sim structurally exact for the quantized data:
// sim_ij = -||x^_i - x^_j||^2 - 100*diag, so diagonal = -100 +- 1e-4) --------
__global__ __launch_bounds__(256) void prep_kernel(const float* __restrict__ x,
                                                   unsigned char* __restrict__ xq,
                                                   float* __restrict__ sq,
                                                   float* __restrict__ out) {
    if (blockIdx.x == 0 && threadIdx.x == 0) out[0] = 0.f;  // for combine's atomics
    const int w = threadIdx.x >> 6, lane = threadIdx.x & 63;
    const int row = blockIdx.x * 4 + w;
    const float4* xr = (const float4*)(x + (size_t)row * GD);
    unsigned int* xqr = (unsigned int*)(xq + (size_t)row * GD);
    float s = 0.f;
#pragma unroll
    for (int i = 0; i < 3; ++i) {
        float4 v = xr[lane + 64 * i];
        __hip_fp8_e4m3 q0(v.x), q1(v.y), q2(v.z), q3(v.w);
        float d0 = (float)q0, d1 = (float)q1, d2 = (float)q2, d3 = (float)q3;
        s += d0 * d0 + d1 * d1 + d2 * d2 + d3 * d3;
        xqr[lane + 64 * i] = (unsigned int)q0.__x | ((unsigned int)q1.__x << 8) |
                             ((unsigned int)q2.__x << 16) | ((unsigned int)q3.__x << 24);
    }
#pragma unroll
    for (int off = 1; off < 64; off <<= 1) s += __shfl_xor(s, off);
    if (lane == 0) sq[row] = s;
}

// ------- Kernel 2: symmetric triangular tile GEMM (MX-fp8, scale=1) + entropy -------
// One 128x128 tile (I,J), J<=I, per WG. 4 waves stacked in M (32 rows x 128 cols).
// NO LDS STAGING: mfma_scale_f32_16x16x128_f8f6f4's per-lane fragment is 32
// contiguous bytes of a row (A[m=cl][k=quad*32+j], mapping verified by R5/R6
// passing), so fragments load global->VGPR directly. Reuse via L1/L2 (matrix is
// 6 MB, L2/L3-resident; all 4 waves share each B-slice -> L1 hits). Zero
// barriers in the K-loop; occupancy VGPR-limited (~12 waves/CU), no collective
// drain stalls (fixes R6's 2-block/CU m132-style latency bind).
// C/D: col=lane&15, row=(lane>>4)*4+reg.
__global__ __launch_bounds__(256) void sym_gemm_entropy(
    const unsigned char* __restrict__ xq, const float* __restrict__ sq,
    const float* __restrict__ taup, float* __restrict__ pm,
    float* __restrict__ ps, float* __restrict__ pt) {
    __shared__ float tmrg[128][4][3];  // 6 KB, used only in the epilogue

    const int tid = threadIdx.x;
    const int lane = tid & 63;
    const int w = tid >> 6;
    const int quad = lane >> 4, cl = lane & 15;

    const int b = blockIdx.x;
    int I = (int)((sqrtf(8.0f * (float)b + 1.0f) - 1.0f) * 0.5f);
    while ((I + 1) * (I + 2) / 2 <= b) ++I;
    while (I * (I + 1) / 2 > b) --I;
    const int J = b - I * (I + 1) / 2;
    const int row_base = I * 128;
    const int col_base = J * 128;
    const float tau = *taup;

    // 32-bit byte offsets of each fragment's row-chunk (matrix is 6 MB)
    const unsigned kq = quad * 32;
    const unsigned rA0 = (unsigned)(row_base + w * 32 + cl) * GD + kq;
    const unsigned rA1 = (unsigned)(row_base + w * 32 + 16 + cl) * GD + kq;
    unsigned rB[8];
#pragma unroll
    for (int tj = 0; tj < 8; ++tj)
        rB[tj] = (unsigned)(col_base + tj * 16 + cl) * GD + kq;

    f32x4 acc[2][8];
#pragma unroll
    for (int i = 0; i < 2; ++i)
#pragma unroll
        for (int j = 0; j < 8; ++j) acc[i][j] = (f32x4){0.f, 0.f, 0.f, 0.f};

#pragma unroll
    for (int kk = 0; kk < KI; ++kk) {
        const unsigned ko = kk * 128;
        i32x8 af0 = ldg32(xq + rA0 + ko);
        i32x8 af1 = ldg32(xq + rA1 + ko);
        i32x8 bf[4];
#pragma unroll
        for (int j = 0; j < 4; ++j) bf[j] = ldg32(xq + rB[j] + ko);

        // depth-4 rotation: issue bf[tj+4]'s load before consuming bf[tj]
#pragma unroll
        for (int tj = 0; tj < 8; ++tj) {
            i32x8 cur = bf[tj & 3];
            if (tj + 4 < 8) bf[tj & 3] = ldg32(xq + rB[tj + 4] + ko);
            acc[0][tj] = __builtin_amdgcn_mfma_scale_f32_16x16x128_f8f6f4(
                af0, cur, acc[0][tj], 0, 0, 0, 0x7F7F7F7F, 0, 0x7F7F7F7F);
            acc[1][tj] = __builtin_amdgcn_mfma_scale_f32_16x16x128_f8f6f4(
                af1, cur, acc[1][tj], 0, 0, 0, 0x7F7F7F7F, 0, 0x7F7F7F7F);
        }
    }

    // per-lane metadata
    float sqr[8];
    int rowg[8];
#pragma unroll
    for (int ti = 0; ti < 2; ++ti)
#pragma unroll
        for (int rg = 0; rg < 4; ++rg) {
            int r = row_base + w * 32 + ti * 16 + quad * 4 + rg;
            rowg[ti * 4 + rg] = r;
            sqr[ti * 4 + rg] = sq[r];
        }
    float sqc[8];
    int colg[8];
#pragma unroll
    for (int tj = 0; tj < 8; ++tj) {
        int c = col_base + tj * 16 + cl;
        colg[tj] = c;
        sqc[tj] = sq[c];
    }

    // ---- direct pass: one (m,S,T) per row of block I over J's 128 cols ----
#pragma unroll
    for (int ti = 0; ti < 2; ++ti)
#pragma unroll
        for (int rg = 0; rg < 4; ++rg) {
            const int idx = ti * 4 + rg;
            float vv[8];
            float mloc = -1e30f;
#pragma unroll
            for (int tj = 0; tj < 8; ++tj) {
                float pen = (rowg[idx] == colg[tj]) ? 100.f : 0.f;
                float v = tau * (2.f * acc[ti][tj][rg] - sqr[idx] - sqc[tj] - pen);
                vv[tj] = v;
                mloc = fmaxf(mloc, v);
            }
#pragma unroll
            for (int mk = 1; mk < 16; mk <<= 1) mloc = fmaxf(mloc, __shfl_xor(mloc, mk));
            float s = 0.f, t = 0.f;
#pragma unroll
            for (int tj = 0; tj < 8; ++tj) {
                float d = vv[tj] - mloc;
                float e = __expf(d);
                s += e;
                t += e * d;
            }
#pragma unroll
            for (int mk = 1; mk < 16; mk <<= 1) {
                s += __shfl_xor(s, mk);
                t += __shfl_xor(t, mk);
            }
            if (cl == 0) {
                int r = rowg[idx];
                pm[(size_t)J * GN + r] = mloc;
                ps[(size_t)J * GN + r] = s;
                pt[(size_t)J * GN + r] = t;
            }
        }

    // ---- transposed pass (off-diagonal tiles): rows of block J over I's rows ----
    if (I != J) {  // block-uniform branch
#pragma unroll
        for (int tj = 0; tj < 8; ++tj) {
            float vv[8];
            float mloc = -1e30f;
#pragma unroll
            for (int ti = 0; ti < 2; ++ti)
#pragma unroll
                for (int rg = 0; rg < 4; ++rg) {
                    float v = tau * (2.f * acc[ti][tj][rg] - sqr[ti * 4 + rg] - sqc[tj]);
                    vv[ti * 4 + rg] = v;
                    mloc = fmaxf(mloc, v);
                }
            mloc = fmaxf(mloc, __shfl_xor(mloc, 16));
            mloc = fmaxf(mloc, __shfl_xor(mloc, 32));
            float s = 0.f, t = 0.f;
#pragma unroll
            for (int k = 0; k < 8; ++k) {
                float d = vv[k] - mloc;
                float e = __expf(d);
                s += e;
                t += e * d;
            }
            s += __shfl_xor(s, 16);
            t += __shfl_xor(t, 16);
            s += __shfl_xor(s, 32);
            t += __shfl_xor(t, 32);
            if (quad == 0) {
                int c = tj * 16 + cl;
                tmrg[c][w][0] = mloc;
                tmrg[c][w][1] = s;
                tmrg[c][w][2] = t;
            }
        }
        __syncthreads();
        if (tid < 128) {
            float m = tmrg[tid][0][0], S = tmrg[tid][0][1], T = tmrg[tid][0][2];
#pragma unroll
            for (int ww = 1; ww < 4; ++ww) {
                float mc = tmrg[tid][ww][0], Sc = tmrg[tid][ww][1], Tc = tmrg[tid][ww][2];
                float mn = fmaxf(m, mc);
                float ea = __expf(m - mn), eb = __expf(mc - mn);
                T = (T + (m - mn) * S) * ea + (Tc + (mc - mn) * Sc) * eb;
                S = S * ea + Sc * eb;
                m = mn;
            }
            int c = col_base + tid;
            pm[(size_t)I * GN + c] = m;
            ps[(size_t)I * GN + c] = S;
            pt[(size_t)I * GN + c] = T;
        }
    }
}

// ---------------- Kernel 3: combine 64 slots -> row entropy -> atomic scalar ----------------
__global__ __launch_bounds__(256) void combine(const float* __restrict__ pm,
                                               const float* __restrict__ ps,
                                               const float* __restrict__ pt,
                                               const float* __restrict__ coefp,
                                               float* __restrict__ out) {
    const int row = blockIdx.x * 256 + threadIdx.x;
    float m = -1e30f, S = 0.f, T = 0.f;
    for (int c = 0; c < NB; ++c) {
        float mc = pm[(size_t)c * GN + row];
        float Sc = ps[(size_t)c * GN + row];
        float Tc = pt[(size_t)c * GN + row];
        float mn = fmaxf(m, mc);
        float ea = __expf(m - mn), eb = __expf(mc - mn);
        T = (T + (m - mn) * S) * ea + (Tc + (mc - mn) * Sc) * eb;
        S = S * ea + Sc * eb;
        m = mn;
    }
    float ent = __logf(S) - T / S;
#pragma unroll
    for (int off = 1; off < 64; off <<= 1) ent += __shfl_xor(ent, off);
    __shared__ float ls[4];
    if ((threadIdx.x & 63) == 0) ls[threadIdx.x >> 6] = ent;
    __syncthreads();
    if (threadIdx.x == 0)
        atomicAdd(out, (ls[0] + ls[1] + ls[2] + ls[3]) * coefp[0] * (1.0f / (float)GN));
}

extern "C" void kernel_launch(void* const* d_in, const int* in_sizes, int n_in,
                              void* d_out, int out_size, void* d_ws, size_t ws_size,
                              hipStream_t stream) {
    const float* x = (const float*)d_in[0];      // 8192*768 fp32
    const float* coefp = (const float*)d_in[1];  // scalar
    const float* taup = (const float*)d_in[2];   // scalar
    float* out = (float*)d_out;

    char* ws = (char*)d_ws;
    unsigned char* xq = (unsigned char*)ws;              // 6,291,456 B (fp8)
    float* sq = (float*)(ws + 6291456);                  // 32,768 B
    float* pm = (float*)(ws + 6324224);                  // 2,097,152 B
    float* ps = (float*)(ws + 6324224 + 2097152);        // 2,097,152 B
    float* pt = (float*)(ws + 6324224 + 2 * 2097152);    // 2,097,152 B

    prep_kernel<<<GN / 4, 256, 0, stream>>>(x, xq, sq, out);
    sym_gemm_entropy<<<NTILE, 256, 0, stream>>>(xq, sq, taup, pm, ps, pt);
    combine<<<GN / 256, 256, 0, stream>>>(pm, ps, pt, coefp, out);
}

// Round 8
// 176.905 us; speedup vs baseline: 1.4726x; 1.4726x over previous
//
#include <hip/hip_runtime.h>
#include <hip/hip_bf16.h>
#include <hip/hip_fp8.h>
#include <cstdint>
#include <cstddef>

// Problem constants (x = (8192, 768) fp32)
#define GN 8192
#define GD 768           // elements per row; fp8 => 768 bytes per row
#define NB 64            // 128-row blocks
#define NTILE 2080       // NB*(NB+1)/2 triangular tiles
#define KSTEPS 24        // 768 / 32 K-iterations (K=32 per MFMA)

typedef __attribute__((ext_vector_type(4))) float f32x4;

typedef __attribute__((address_space(1))) const unsigned int gu32;
typedef __attribute__((address_space(3))) unsigned int lu32;

__device__ __forceinline__ void gl2lds16(const void* g, void* l) {
    // async global->LDS, 16B per lane; LDS dest is wave-uniform base + lane*16
    __builtin_amdgcn_global_load_lds((gu32*)g, (lu32*)l, 16, 0, 0);
}

// fp8 tile LDS layout: 128 rows x 32 B. 4 rows pack one 128 B superrow
// (sr = r>>2) of 16 x 8 B slots; logical slot l = (r&3)*4 + q (q = 8B k-unit).
// phys = l ^ ((sr&7)<<1)  -- bit0-preserving XOR: breaks row aliasing (<=2-way,
// free per m136) while keeping each 16 B staging write k-contiguous.
__device__ __forceinline__ int swz8(int r, int q) {
    return (r >> 2) * 128 + ((((r & 3) * 4 + q) ^ (((r >> 2) & 7) << 1)) << 3);
}

// ---------------- Kernel 1: fp8 e4m3 quantize + row sum-of-squares of the
// DEQUANTIZED values (makes sim structurally exact for the quantized data:
// sim_ij = -||x^_i - x^_j||^2 - 100*diag, so diagonal = -100 dominates) -----
__global__ __launch_bounds__(256) void prep_kernel(const float* __restrict__ x,
                                                   unsigned char* __restrict__ xq,
                                                   float* __restrict__ sq,
                                                   float* __restrict__ out) {
    if (blockIdx.x == 0 && threadIdx.x == 0) out[0] = 0.f;  // for combine's atomics
    const int w = threadIdx.x >> 6, lane = threadIdx.x & 63;
    const int row = blockIdx.x * 4 + w;
    const float4* xr = (const float4*)(x + (size_t)row * GD);
    unsigned int* xqr = (unsigned int*)(xq + (size_t)row * GD);
    float s = 0.f;
#pragma unroll
    for (int i = 0; i < 3; ++i) {
        float4 v = xr[lane + 64 * i];
        __hip_fp8_e4m3 q0(v.x), q1(v.y), q2(v.z), q3(v.w);
        float d0 = (float)q0, d1 = (float)q1, d2 = (float)q2, d3 = (float)q3;
        s += d0 * d0 + d1 * d1 + d2 * d2 + d3 * d3;
        xqr[lane + 64 * i] = (unsigned int)q0.__x | ((unsigned int)q1.__x << 8) |
                             ((unsigned int)q2.__x << 16) | ((unsigned int)q3.__x << 24);
    }
#pragma unroll
    for (int off = 1; off < 64; off <<= 1) s += __shfl_xor(s, off);
    if (lane == 0) sq[row] = s;
}

// ------- Kernel 2: symmetric triangular tile GEMM (fp8 16x16x32) + entropy -------
// R4's proven structure, fp8 dtype. One 128x128 tile (I,J), J<=I, per WG; 4 waves
// stacked in M (32 rows x 128 cols each). Double-buffered 2x8 KB LDS; K-loop body:
// barrier -> ds_read all 10 frags (b64) -> issue stage(k+1) -> 16 MFMA.
// A frag = 8 contiguous k-bytes at k=quad*8 (contiguity verified via R5/R7 passes).
// C/D: col=lane&15, row=(lane>>4)*4+reg (dtype-independent, verified).
__global__ __launch_bounds__(256) void sym_gemm_entropy(
    const unsigned char* __restrict__ xq, const float* __restrict__ sq,
    const float* __restrict__ taup, float* __restrict__ pm,
    float* __restrict__ ps, float* __restrict__ pt) {
    __shared__ __align__(16) char lds[16384];  // [A0 4K][B0 4K][A1 4K][B1 4K]
    float (*tmrg)[4][3] = (float (*)[4][3])lds;  // aliased; guarded by barrier

    const int tid = threadIdx.x;
    const int lane = tid & 63;
    const int w = tid >> 6;
    const int quad = lane >> 4, cl = lane & 15;

    const int b = blockIdx.x;
    int I = (int)((sqrtf(8.0f * (float)b + 1.0f) - 1.0f) * 0.5f);
    while ((I + 1) * (I + 2) / 2 <= b) ++I;
    while (I * (I + 1) / 2 > b) --I;
    const int J = b - I * (I + 1) / 2;
    const int row_base = I * 128;
    const int col_base = J * 128;
    const float tau = *taup;

    // staging decode: thread t's 16 B LDS slot (t*16) = superrow t>>3, phys 8B-slots
    // {2(t&7), 2(t&7)+1}; invert the swizzle to find the global (row, k-offset)
    const int sr = tid >> 3;
    const int l0 = ((tid & 7) << 1) ^ ((sr & 7) << 1);  // even logical slot
    const int srow = sr * 4 + (l0 >> 2);                // 0..127
    const int skb = (l0 & 3) * 8;                       // 0 or 16 (bytes in 32B chunk)
    const unsigned char* gA = xq + (size_t)(row_base + srow) * GD + skb;
    const unsigned char* gB = xq + (size_t)(col_base + srow) * GD + skb;

    // fragment LDS offsets (b64 each): A rows m = w*32 + ti*16 + cl; B rows n
    int offA[2], offB[8];
#pragma unroll
    for (int ti = 0; ti < 2; ++ti) offA[ti] = swz8(w * 32 + ti * 16 + cl, quad);
#pragma unroll
    for (int tj = 0; tj < 8; ++tj) offB[tj] = swz8(tj * 16 + cl, quad);

    f32x4 acc[2][8];
#pragma unroll
    for (int i = 0; i < 2; ++i)
#pragma unroll
        for (int j = 0; j < 8; ++j) acc[i][j] = (f32x4){0.f, 0.f, 0.f, 0.f};

    // prologue: stage k=0 into buffer 0 (A 4 KB + B 4 KB, 1 load each per thread)
    gl2lds16(gA, lds + tid * 16);
    gl2lds16(gB, lds + 4096 + tid * 16);

#pragma unroll 2
    for (int kk = 0; kk < KSTEPS; ++kk) {
        __syncthreads();  // buf[kk&1] staged; prior buf's ds_reads done

        // 1) read ALL fragments of this iter (10 x ds_read_b64, ~20 regs)
        const char* Ab = lds + (kk & 1) * 8192;
        const char* Bb = Ab + 4096;
        long af[2], bf[8];
#pragma unroll
        for (int ti = 0; ti < 2; ++ti) af[ti] = *(const long*)(Ab + offA[ti]);
#pragma unroll
        for (int tj = 0; tj < 8; ++tj) bf[tj] = *(const long*)(Bb + offB[tj]);

        // 2) stage k+1 into the other buffer; flies over the MFMA phase and
        //    drains at the next barrier
        if (kk + 1 < KSTEPS) {
            char* An = lds + ((kk + 1) & 1) * 8192;
            const int ko = (kk + 1) * 32;  // bytes along K
            gl2lds16(gA + ko, An + tid * 16);
            gl2lds16(gB + ko, An + 4096 + tid * 16);
        }

        // 3) MFMAs
#pragma unroll
        for (int ti = 0; ti < 2; ++ti)
#pragma unroll
            for (int tj = 0; tj < 8; ++tj)
                acc[ti][tj] = __builtin_amdgcn_mfma_f32_16x16x32_fp8_fp8(
                    af[ti], bf[tj], acc[ti][tj], 0, 0, 0);
    }

    // per-lane metadata
    float sqr[8];
    int rowg[8];
#pragma unroll
    for (int ti = 0; ti < 2; ++ti)
#pragma unroll
        for (int rg = 0; rg < 4; ++rg) {
            int r = row_base + w * 32 + ti * 16 + quad * 4 + rg;
            rowg[ti * 4 + rg] = r;
            sqr[ti * 4 + rg] = sq[r];
        }
    float sqc[8];
    int colg[8];
#pragma unroll
    for (int tj = 0; tj < 8; ++tj) {
        int c = col_base + tj * 16 + cl;
        colg[tj] = c;
        sqc[tj] = sq[c];
    }

    // ---- direct pass: one (m,S,T) per row of block I over J's 128 cols ----
#pragma unroll
    for (int ti = 0; ti < 2; ++ti)
#pragma unroll
        for (int rg = 0; rg < 4; ++rg) {
            const int idx = ti * 4 + rg;
            float vv[8];
            float mloc = -1e30f;
#pragma unroll
            for (int tj = 0; tj < 8; ++tj) {
                float pen = (rowg[idx] == colg[tj]) ? 100.f : 0.f;
                float v = tau * (2.f * acc[ti][tj][rg] - sqr[idx] - sqc[tj] - pen);
                vv[tj] = v;
                mloc = fmaxf(mloc, v);
            }
#pragma unroll
            for (int mk = 1; mk < 16; mk <<= 1) mloc = fmaxf(mloc, __shfl_xor(mloc, mk));
            float s = 0.f, t = 0.f;
#pragma unroll
            for (int tj = 0; tj < 8; ++tj) {
                float d = vv[tj] - mloc;
                float e = __expf(d);
                s += e;
                t += e * d;
            }
#pragma unroll
            for (int mk = 1; mk < 16; mk <<= 1) {
                s += __shfl_xor(s, mk);
                t += __shfl_xor(t, mk);
            }
            if (cl == 0) {
                int r = rowg[idx];
                pm[(size_t)J * GN + r] = mloc;
                ps[(size_t)J * GN + r] = s;
                pt[(size_t)J * GN + r] = t;
            }
        }

    // ---- transposed pass (off-diagonal tiles): rows of block J over I's rows ----
    if (I != J) {  // block-uniform branch
        __syncthreads();  // all K-loop LDS reads done before tmrg aliases the buffer
#pragma unroll
        for (int tj = 0; tj < 8; ++tj) {
            float vv[8];
            float mloc = -1e30f;
#pragma unroll
            for (int ti = 0; ti < 2; ++ti)
#pragma unroll
                for (int rg = 0; rg < 4; ++rg) {
                    float v = tau * (2.f * acc[ti][tj][rg] - sqr[ti * 4 + rg] - sqc[tj]);
                    vv[ti * 4 + rg] = v;
                    mloc = fmaxf(mloc, v);
                }
            mloc = fmaxf(mloc, __shfl_xor(mloc, 16));
            mloc = fmaxf(mloc, __shfl_xor(mloc, 32));
            float s = 0.f, t = 0.f;
#pragma unroll
            for (int k = 0; k < 8; ++k) {
                float d = vv[k] - mloc;
                float e = __expf(d);
                s += e;
                t += e * d;
            }
            s += __shfl_xor(s, 16);
            t += __shfl_xor(t, 16);
            s += __shfl_xor(s, 32);
            t += __shfl_xor(t, 32);
            if (quad == 0) {
                int c = tj * 16 + cl;
                tmrg[c][w][0] = mloc;
                tmrg[c][w][1] = s;
                tmrg[c][w][2] = t;
            }
        }
        __syncthreads();
        if (tid < 128) {
            float m = tmrg[tid][0][0], S = tmrg[tid][0][1], T = tmrg[tid][0][2];
#pragma unroll
            for (int ww = 1; ww < 4; ++ww) {
                float mc = tmrg[tid][ww][0], Sc = tmrg[tid][ww][1], Tc = tmrg[tid][ww][2];
                float mn = fmaxf(m, mc);
                float ea = __expf(m - mn), eb = __expf(mc - mn);
                T = (T + (m - mn) * S) * ea + (Tc + (mc - mn) * Sc) * eb;
                S = S * ea + Sc * eb;
                m = mn;
            }
            int c = col_base + tid;
            pm[(size_t)I * GN + c] = m;
            ps[(size_t)I * GN + c] = S;
            pt[(size_t)I * GN + c] = T;
        }
    }
}

// ---------------- Kernel 3: combine 64 slots -> row entropy -> atomic scalar ----------------
__global__ __launch_bounds__(256) void combine(const float* __restrict__ pm,
                                               const float* __restrict__ ps,
                                               const float* __restrict__ pt,
                                               const float* __restrict__ coefp,
                                               float* __restrict__ out) {
    const int row = blockIdx.x * 256 + threadIdx.x;
    float m = -1e30f, S = 0.f, T = 0.f;
    for (int c = 0; c < NB; ++c) {
        float mc = pm[(size_t)c * GN + row];
        float Sc = ps[(size_t)c * GN + row];
        float Tc = pt[(size_t)c * GN + row];
        float mn = fmaxf(m, mc);
        float ea = __expf(m - mn), eb = __expf(mc - mn);
        T = (T + (m - mn) * S) * ea + (Tc + (mc - mn) * Sc) * eb;
        S = S * ea + Sc * eb;
        m = mn;
    }
    float ent = __logf(S) - T / S;
#pragma unroll
    for (int off = 1; off < 64; off <<= 1) ent += __shfl_xor(ent, off);
    __shared__ float ls[4];
    if ((threadIdx.x & 63) == 0) ls[threadIdx.x >> 6] = ent;
    __syncthreads();
    if (threadIdx.x == 0)
        atomicAdd(out, (ls[0] + ls[1] + ls[2] + ls[3]) * coefp[0] * (1.0f / (float)GN));
}

extern "C" void kernel_launch(void* const* d_in, const int* in_sizes, int n_in,
                              void* d_out, int out_size, void* d_ws, size_t ws_size,
                              hipStream_t stream) {
    const float* x = (const float*)d_in[0];      // 8192*768 fp32
    const float* coefp = (const float*)d_in[1];  // scalar
    const float* taup = (const float*)d_in[2];   // scalar
    float* out = (float*)d_out;

    char* ws = (char*)d_ws;
    unsigned char* xq = (unsigned char*)ws;              // 6,291,456 B (fp8)
    float* sq = (float*)(ws + 6291456);                  // 32,768 B
    float* pm = (float*)(ws + 6324224);                  // 2,097,152 B
    float* ps = (float*)(ws + 6324224 + 2097152);        // 2,097,152 B
    float* pt = (float*)(ws + 6324224 + 2 * 2097152);    // 2,097,152 B

    prep_kernel<<<GN / 4, 256, 0, stream>>>(x, xq, sq, out);
    sym_gemm_entropy<<<NTILE, 256, 0, stream>>>(xq, sq, taup, pm, ps, pt);
    combine<<<GN / 256, 256, 0, stream>>>(pm, ps, pt, coefp, out);
}

// Round 9
// 153.867 us; speedup vs baseline: 1.6931x; 1.1497x over previous
//
#include <hip/hip_runtime.h>
#include <hip/hip_bf16.h>
#include <hip/hip_fp8.h>
#include <cstdint>
#include <cstddef>

// Problem constants (x = (8192, 768) fp32)
#define GN 8192
#define GD 768           // elements per row; fp8 => 768 bytes per row
#define NB 64            // 128-row blocks
#define NTILE 2080       // NB*(NB+1)/2 triangular tiles
#define KI 12            // 768 / 64 : K-iterations, 64 bytes (2 MFMA k-steps) each

typedef __attribute__((ext_vector_type(4))) float f32x4;
typedef __attribute__((ext_vector_type(2))) long l64x2;  // one b128 = 2 fp8 fragments

typedef __attribute__((address_space(1))) const unsigned int gu32;
typedef __attribute__((address_space(3))) unsigned int lu32;

__device__ __forceinline__ void gl2lds16(const void* g, void* l) {
    // async global->LDS, 16B per lane; LDS dest is wave-uniform base + lane*16
    __builtin_amdgcn_global_load_lds((gu32*)g, (lu32*)l, 16, 0, 0);
}

// R4's PROVEN swizzle (measured 1.9e5 conflicts), reused byte-identically:
// row = 64 B = 4 x 16B units; rows paired into 128 B superrows (sr = r>>1);
// logical unit l = ((r&1)<<2)|q (q = 16B k-unit 0..3); phys = l ^ (sr&7).
__device__ __forceinline__ int swz(int r, int q) {
    return ((r >> 1) << 7) + (((((r & 1) << 2) | q) ^ ((r >> 1) & 7)) << 4);
}

// ---------------- Kernel 1: fp8 e4m3 quantize + row sum-of-squares of the
// DEQUANTIZED values (makes sim structurally exact for the quantized data:
// sim_ij = -||x^_i - x^_j||^2 - 100*diag, so diagonal = -100 dominates) -----
__global__ __launch_bounds__(256) void prep_kernel(const float* __restrict__ x,
                                                   unsigned char* __restrict__ xq,
                                                   float* __restrict__ sq,
                                                   float* __restrict__ out) {
    if (blockIdx.x == 0 && threadIdx.x == 0) out[0] = 0.f;  // for combine's atomics
    const int w = threadIdx.x >> 6, lane = threadIdx.x & 63;
    const int row = blockIdx.x * 4 + w;
    const float4* xr = (const float4*)(x + (size_t)row * GD);
    unsigned int* xqr = (unsigned int*)(xq + (size_t)row * GD);
    float s = 0.f;
#pragma unroll
    for (int i = 0; i < 3; ++i) {
        float4 v = xr[lane + 64 * i];
        __hip_fp8_e4m3 q0(v.x), q1(v.y), q2(v.z), q3(v.w);
        float d0 = (float)q0, d1 = (float)q1, d2 = (float)q2, d3 = (float)q3;
        s += d0 * d0 + d1 * d1 + d2 * d2 + d3 * d3;
        xqr[lane + 64 * i] = (unsigned int)q0.__x | ((unsigned int)q1.__x << 8) |
                             ((unsigned int)q2.__x << 16) | ((unsigned int)q3.__x << 24);
    }
#pragma unroll
    for (int off = 1; off < 64; off <<= 1) s += __shfl_xor(s, off);
    if (lane == 0) sq[row] = s;
}

// ------- Kernel 2: symmetric triangular tile GEMM (fp8, k-paired) + entropy -------
// One 128x128 tile (I,J), J<=I, per WG; 4 waves stacked in M (32 rows x 128 cols).
// K-pairing: each 64-B row chunk is split so lane-quad q owns global bytes
// [q*16, q*16+16) -- ONE ds_read_b128 feeds TWO mfma_f32_16x16x32_fp8_fp8
// (.x = first 8 bytes, .y = second 8; same permutation on A and B => exact).
// Body: barrier -> read all 10 b128 -> issue stage(k+1) -> 32 MFMA.
// C/D: col=lane&15, row=(lane>>4)*4+reg (dtype-independent, verified).
__global__ __launch_bounds__(256) void sym_gemm_entropy(
    const unsigned char* __restrict__ xq, const float* __restrict__ sq,
    const float* __restrict__ taup, float* __restrict__ pm,
    float* __restrict__ ps, float* __restrict__ pt) {
    __shared__ __align__(16) char lds[32768];  // [A0 8K][B0 8K][A1 8K][B1 8K]
    float (*tmrg)[4][3] = (float (*)[4][3])lds;  // aliased; guarded by barrier

    const int tid = threadIdx.x;
    const int lane = tid & 63;
    const int w = tid >> 6;
    const int quad = lane >> 4, cl = lane & 15;

    const int b = blockIdx.x;
    int I = (int)((sqrtf(8.0f * (float)b + 1.0f) - 1.0f) * 0.5f);
    while ((I + 1) * (I + 2) / 2 <= b) ++I;
    while (I * (I + 1) / 2 > b) --I;
    const int J = b - I * (I + 1) / 2;
    const int row_base = I * 128;
    const int col_base = J * 128;
    const float tau = *taup;

    // staging decode (R4's proven inverse-swizzle): thread t stages LDS slot t*16
    // (rows 0..63) and +4096 (rows 64..127, same swizzle phase since 32%8==0)
    const int bb = (tid & 7) ^ ((tid >> 3) & 7);
    const int sRow = ((tid >> 3) << 1) | (bb >> 2);  // 0..63
    const int sKb = (bb & 3) * 16;                   // byte offset in 64-B chunk
    const unsigned char* gA = xq + (size_t)(row_base + sRow) * GD + sKb;
    const unsigned char* gB = xq + (size_t)(col_base + sRow) * GD + sKb;

    // fragment LDS offsets (one b128 per tile-row): unit q = quad
    int offA[2], offB[8];
#pragma unroll
    for (int ti = 0; ti < 2; ++ti) offA[ti] = swz(w * 32 + ti * 16 + cl, quad);
#pragma unroll
    for (int tj = 0; tj < 8; ++tj) offB[tj] = swz(tj * 16 + cl, quad);

    f32x4 acc[2][8];
#pragma unroll
    for (int i = 0; i < 2; ++i)
#pragma unroll
        for (int j = 0; j < 8; ++j) acc[i][j] = (f32x4){0.f, 0.f, 0.f, 0.f};

    // prologue: stage k=0 into buffer 0 (A 8 KB + B 8 KB, 2 loads each per thread)
    gl2lds16(gA, lds + tid * 16);
    gl2lds16(gA + (size_t)64 * GD, lds + 4096 + tid * 16);
    gl2lds16(gB, lds + 8192 + tid * 16);
    gl2lds16(gB + (size_t)64 * GD, lds + 12288 + tid * 16);

#pragma unroll 2
    for (int kk = 0; kk < KI; ++kk) {
        __syncthreads();  // buf[kk&1] staged; prior buf's ds_reads done

        // 1) read ALL fragments of this iter (10 x ds_read_b128)
        const char* Ab = lds + (kk & 1) * 16384;
        const char* Bb = Ab + 8192;
        l64x2 aF[2], bF[8];
#pragma unroll
        for (int ti = 0; ti < 2; ++ti) aF[ti] = *(const l64x2*)(Ab + offA[ti]);
#pragma unroll
        for (int tj = 0; tj < 8; ++tj) bF[tj] = *(const l64x2*)(Bb + offB[tj]);

        // 2) stage k+1 into the other buffer; drains at the next barrier
        if (kk + 1 < KI) {
            char* An = lds + ((kk + 1) & 1) * 16384;
            const int ko = (kk + 1) * 64;  // bytes along K
            gl2lds16(gA + ko, An + tid * 16);
            gl2lds16(gA + (size_t)64 * GD + ko, An + 4096 + tid * 16);
            gl2lds16(gB + ko, An + 8192 + tid * 16);
            gl2lds16(gB + (size_t)64 * GD + ko, An + 12288 + tid * 16);
        }

        // 3) 32 MFMAs: each b128 pair feeds two K=32 fp8 MFMAs
#pragma unroll
        for (int ti = 0; ti < 2; ++ti)
#pragma unroll
            for (int tj = 0; tj < 8; ++tj) {
                acc[ti][tj] = __builtin_amdgcn_mfma_f32_16x16x32_fp8_fp8(
                    aF[ti].x, bF[tj].x, acc[ti][tj], 0, 0, 0);
                acc[ti][tj] = __builtin_amdgcn_mfma_f32_16x16x32_fp8_fp8(
                    aF[ti].y, bF[tj].y, acc[ti][tj], 0, 0, 0);
            }
    }

    // per-lane metadata
    float sqr[8];
    int rowg[8];
#pragma unroll
    for (int ti = 0; ti < 2; ++ti)
#pragma unroll
        for (int rg = 0; rg < 4; ++rg) {
            int r = row_base + w * 32 + ti * 16 + quad * 4 + rg;
            rowg[ti * 4 + rg] = r;
            sqr[ti * 4 + rg] = sq[r];
        }
    float sqc[8];
    int colg[8];
#pragma unroll
    for (int tj = 0; tj < 8; ++tj) {
        int c = col_base + tj * 16 + cl;
        colg[tj] = c;
        sqc[tj] = sq[c];
    }

    // ---- direct pass: one (m,S,T) per row of block I over J's 128 cols ----
#pragma unroll
    for (int ti = 0; ti < 2; ++ti)
#pragma unroll
        for (int rg = 0; rg < 4; ++rg) {
            const int idx = ti * 4 + rg;
            float vv[8];
            float mloc = -1e30f;
#pragma unroll
            for (int tj = 0; tj < 8; ++tj) {
                float pen = (rowg[idx] == colg[tj]) ? 100.f : 0.f;
                float v = tau * (2.f * acc[ti][tj][rg] - sqr[idx] - sqc[tj] - pen);
                vv[tj] = v;
                mloc = fmaxf(mloc, v);
            }
#pragma unroll
            for (int mk = 1; mk < 16; mk <<= 1) mloc = fmaxf(mloc, __shfl_xor(mloc, mk));
            float s = 0.f, t = 0.f;
#pragma unroll
            for (int tj = 0; tj < 8; ++tj) {
                float d = vv[tj] - mloc;
                float e = __expf(d);
                s += e;
                t += e * d;
            }
#pragma unroll
            for (int mk = 1; mk < 16; mk <<= 1) {
                s += __shfl_xor(s, mk);
                t += __shfl_xor(t, mk);
            }
            if (cl == 0) {
                int r = rowg[idx];
                pm[(size_t)J * GN + r] = mloc;
                ps[(size_t)J * GN + r] = s;
                pt[(size_t)J * GN + r] = t;
            }
        }

    // ---- transposed pass (off-diagonal tiles): rows of block J over I's rows ----
    if (I != J) {  // block-uniform branch
        __syncthreads();  // all K-loop LDS reads done before tmrg aliases the buffer
#pragma unroll
        for (int tj = 0; tj < 8; ++tj) {
            float vv[8];
            float mloc = -1e30f;
#pragma unroll
            for (int ti = 0; ti < 2; ++ti)
#pragma unroll
                for (int rg = 0; rg < 4; ++rg) {
                    float v = tau * (2.f * acc[ti][tj][rg] - sqr[ti * 4 + rg] - sqc[tj]);
                    vv[ti * 4 + rg] = v;
                    mloc = fmaxf(mloc, v);
                }
            mloc = fmaxf(mloc, __shfl_xor(mloc, 16));
            mloc = fmaxf(mloc, __shfl_xor(mloc, 32));
            float s = 0.f, t = 0.f;
#pragma unroll
            for (int k = 0; k < 8; ++k) {
                float d = vv[k] - mloc;
                float e = __expf(d);
                s += e;
                t += e * d;
            }
            s += __shfl_xor(s, 16);
            t += __shfl_xor(t, 16);
            s += __shfl_xor(s, 32);
            t += __shfl_xor(t, 32);
            if (quad == 0) {
                int c = tj * 16 + cl;
                tmrg[c][w][0] = mloc;
                tmrg[c][w][1] = s;
                tmrg[c][w][2] = t;
            }
        }
        __syncthreads();
        if (tid < 128) {
            float m = tmrg[tid][0][0], S = tmrg[tid][0][1], T = tmrg[tid][0][2];
#pragma unroll
            for (int ww = 1; ww < 4; ++ww) {
                float mc = tmrg[tid][ww][0], Sc = tmrg[tid][ww][1], Tc = tmrg[tid][ww][2];
                float mn = fmaxf(m, mc);
                float ea = __expf(m - mn), eb = __expf(mc - mn);
                T = (T + (m - mn) * S) * ea + (Tc + (mc - mn) * Sc) * eb;
                S = S * ea + Sc * eb;
                m = mn;
            }
            int c = col_base + tid;
            pm[(size_t)I * GN + c] = m;
            ps[(size_t)I * GN + c] = S;
            pt[(size_t)I * GN + c] = T;
        }
    }
}

// ---------------- Kernel 3: combine 64 slots -> row entropy -> atomic scalar ----------------
__global__ __launch_bounds__(256) void combine(const float* __restrict__ pm,
                                               const float* __restrict__ ps,
                                               const float* __restrict__ pt,
                                               const float* __restrict__ coefp,
                                               float* __restrict__ out) {
    const int row = blockIdx.x * 256 + threadIdx.x;
    float m = -1e30f, S = 0.f, T = 0.f;
    for (int c = 0; c < NB; ++c) {
        float mc = pm[(size_t)c * GN + row];
        float Sc = ps[(size_t)c * GN + row];
        float Tc = pt[(size_t)c * GN + row];
        float mn = fmaxf(m, mc);
        float ea = __expf(m - mn), eb = __expf(mc - mn);
        T = (T + (m - mn) * S) * ea + (Tc + (mc - mn) * Sc) * eb;
        S = S * ea + Sc * eb;
        m = mn;
    }
    float ent = __logf(S) - T / S;
#pragma unroll
    for (int off = 1; off < 64; off <<= 1) ent += __shfl_xor(ent, off);
    __shared__ float ls[4];
    if ((threadIdx.x & 63) == 0) ls[threadIdx.x >> 6] = ent;
    __syncthreads();
    if (threadIdx.x == 0)
        atomicAdd(out, (ls[0] + ls[1] + ls[2] + ls[3]) * coefp[0] * (1.0f / (float)GN));
}

extern "C" void kernel_launch(void* const* d_in, const int* in_sizes, int n_in,
                              void* d_out, int out_size, void* d_ws, size_t ws_size,
                              hipStream_t stream) {
    const float* x = (const float*)d_in[0];      // 8192*768 fp32
    const float* coefp = (const float*)d_in[1];  // scalar
    const float* taup = (const float*)d_in[2];   // scalar
    float* out = (float*)d_out;

    char* ws = (char*)d_ws;
    unsigned char* xq = (unsigned char*)ws;              // 6,291,456 B (fp8)
    float* sq = (float*)(ws + 6291456);                  // 32,768 B
    float* pm = (float*)(ws + 6324224);                  // 2,097,152 B
    float* ps = (float*)(ws + 6324224 + 2097152);        // 2,097,152 B
    float* pt = (float*)(ws + 6324224 + 2 * 2097152);    // 2,097,152 B

    prep_kernel<<<GN / 4, 256, 0, stream>>>(x, xq, sq, out);
    sym_gemm_entropy<<<NTILE, 256, 0, stream>>>(xq, sq, taup, pm, ps, pt);
    combine<<<GN / 256, 256, 0, stream>>>(pm, ps, pt, coefp, out);
}